// Round 11
// baseline (246.395 us; speedup 1.0000x reference)
//
#include <hip/hip_runtime.h>

// ---------------------------------------------------------------------------
// GCN 2-layer: out = A_n @ relu(A_n @ (x W1) + b1) W2 + b2,  A_n = D^-1/2 A D^-1/2
// N=50000 nodes, E=800000 edges (+ implicit self loops), F: 128 -> 128 -> 64.
// CSR by dst, dense fp32 GEMMs (B-in-LDS), wave-per-node gather.
// R8: agg latency-bound. R9: 4xMLP 68->58us. R10: 8xMLP + csr_w -> no change;
//   agg1(512B rows) == agg2(256B rows) == 57us, FETCH invariant ->
//   bound by GATHER-INSTRUCTION RATE (~1 vector load per edge), not bytes.
// R11: 16B/lane float4 gathers -> lanes split into row-groups:
//   F=128: 2 edges/load (32 lanes x float4 = row), F=64: 4 edges/load.
//   Edge ids via one per-lane-indexed shfl; cross-group combine at end.
// ---------------------------------------------------------------------------

#define N_NODES 50000
#define N_EDGES 800000

// workspace layout (bytes, all 256-aligned)
static constexpr size_t OFF_DEG  = 0;         // int[50000]
static constexpr size_t OFF_CUR  = 200192;    // int[50000]
static constexpr size_t OFF_ROW  = 400384;    // int[50001]
static constexpr size_t OFF_BS   = 600576;    // int[256]
static constexpr size_t OFF_DINV = 601600;    // float[50000]
static constexpr size_t OFF_CSR  = 801792;    // int[800000]
static constexpr size_t OFF_CSRW = 4001792;   // float[800000]
static constexpr size_t OFF_H1   = 7201792;   // float[50000*128]  (reused as h2)
static constexpr size_t OFF_OUT1 = 32801792;  // float[50000*128]
// total ~58.4 MB

__global__ __launch_bounds__(256) void count_deg_k(const int* __restrict__ ei,
                                                   int* __restrict__ deg) {
    int e = blockIdx.x * 256 + threadIdx.x;
    if (e < N_EDGES) {
        int d = ei[N_EDGES + e];
        if ((unsigned)d < N_NODES) atomicAdd(&deg[d], 1);
    }
}

// block-scan of deg -> row_start + per-block sums; also emits dinv.
__global__ __launch_bounds__(256) void scan1_k(const int* __restrict__ deg,
                                               int* __restrict__ row_start,
                                               int* __restrict__ bsums,
                                               float* __restrict__ dinv) {
    __shared__ int sm[256];
    int tid = threadIdx.x;
    int i = blockIdx.x * 256 + tid;
    int v = (i < N_NODES) ? deg[i] : 0;
    if (i < N_NODES) dinv[i] = rsqrtf((float)(v + 1));
    sm[tid] = v;
    __syncthreads();
    #pragma unroll
    for (int off = 1; off < 256; off <<= 1) {
        int t = (tid >= off) ? sm[tid - off] : 0;
        __syncthreads();
        sm[tid] += t;
        __syncthreads();
    }
    if (i < N_NODES) row_start[i] = sm[tid] - v;
    if (tid == 255) bsums[blockIdx.x] = sm[255];
}

__global__ __launch_bounds__(256) void scan2_k(int* __restrict__ bsums, int nb) {
    __shared__ int sm[256];
    int tid = threadIdx.x;
    int v = (tid < nb) ? bsums[tid] : 0;
    sm[tid] = v;
    __syncthreads();
    #pragma unroll
    for (int off = 1; off < 256; off <<= 1) {
        int t = (tid >= off) ? sm[tid - off] : 0;
        __syncthreads();
        sm[tid] += t;
        __syncthreads();
    }
    if (tid < nb) bsums[tid] = sm[tid] - v;  // exclusive block offsets
}

__global__ __launch_bounds__(256) void scan3_k(int* __restrict__ row_start,
                                               const int* __restrict__ bsums) {
    int i = blockIdx.x * 256 + threadIdx.x;
    if (i < N_NODES) row_start[i] += bsums[blockIdx.x];
    if (i == 0) row_start[N_NODES] = N_EDGES;
}

__global__ __launch_bounds__(256) void fill_k(const int* __restrict__ ei,
                                              const int* __restrict__ row_start,
                                              int* __restrict__ cursor,
                                              const float* __restrict__ dinv,
                                              int* __restrict__ csr_src,
                                              float* __restrict__ csr_w) {
    int e = blockIdx.x * 256 + threadIdx.x;
    if (e < N_EDGES) {
        int s = ei[e];
        int d = ei[N_EDGES + e];
        if ((unsigned)d < N_NODES && (unsigned)s < N_NODES) {
            int pos = row_start[d] + atomicAdd(&cursor[d], 1);
            if ((unsigned)pos < N_EDGES) {
                csr_src[pos] = s;
                csr_w[pos] = dinv[s];
            }
        }
    }
}

// ---------------------------------------------------------------------------
// fp32 GEMM with whole-B-in-LDS. C[M][N] = A[M][128] * B[128][N].
// Block: 256 threads, BM=64 rows x BN=64 cols. grid = (ceil(M/64), N/64).
// ---------------------------------------------------------------------------
template <int N>
__global__ __launch_bounds__(256, 4) void gemm_blds(const float* __restrict__ A,
                                                    const float* __restrict__ B,
                                                    float* __restrict__ C, int M) {
    constexpr int K = 128, BM = 64, BN = 64, PAD = 4;
    __shared__ float Bs[K][BN + PAD];   // 34816 B

    const int tid = threadIdx.x;
    const int nBase = blockIdx.y * BN;

    #pragma unroll
    for (int p = 0; p < 8; ++p) {
        int fi = tid + p * 256;
        int row = fi >> 4;            // 0..127
        int c4 = (fi & 15) * 4;       // 0..60
        float4 t = *(const float4*)&B[(size_t)row * N + nBase + c4];
        *(float4*)&Bs[row][c4] = t;
    }
    __syncthreads();

    const int tx = tid & 15, ty = tid >> 4;
    const int m0 = blockIdx.x * BM + ty * 4;
    const int n0 = tx * 4;

    const float* A0 = A + (size_t)(m0 + 0 < M ? m0 + 0 : M - 1) * K;
    const float* A1 = A + (size_t)(m0 + 1 < M ? m0 + 1 : M - 1) * K;
    const float* A2 = A + (size_t)(m0 + 2 < M ? m0 + 2 : M - 1) * K;
    const float* A3 = A + (size_t)(m0 + 3 < M ? m0 + 3 : M - 1) * K;

    float acc[4][4] = {};

    #pragma unroll 4
    for (int kq = 0; kq < K / 4; ++kq) {
        float4 a0 = *(const float4*)&A0[kq * 4];
        float4 a1 = *(const float4*)&A1[kq * 4];
        float4 a2 = *(const float4*)&A2[kq * 4];
        float4 a3 = *(const float4*)&A3[kq * 4];
        #pragma unroll
        for (int kk = 0; kk < 4; ++kk) {
            int k = kq * 4 + kk;
            float4 bv = *(const float4*)&Bs[k][n0];
            float av0 = kk == 0 ? a0.x : kk == 1 ? a0.y : kk == 2 ? a0.z : a0.w;
            float av1 = kk == 0 ? a1.x : kk == 1 ? a1.y : kk == 2 ? a1.z : a1.w;
            float av2 = kk == 0 ? a2.x : kk == 1 ? a2.y : kk == 2 ? a2.z : a2.w;
            float av3 = kk == 0 ? a3.x : kk == 1 ? a3.y : kk == 2 ? a3.z : a3.w;
            acc[0][0] = fmaf(av0, bv.x, acc[0][0]);
            acc[0][1] = fmaf(av0, bv.y, acc[0][1]);
            acc[0][2] = fmaf(av0, bv.z, acc[0][2]);
            acc[0][3] = fmaf(av0, bv.w, acc[0][3]);
            acc[1][0] = fmaf(av1, bv.x, acc[1][0]);
            acc[1][1] = fmaf(av1, bv.y, acc[1][1]);
            acc[1][2] = fmaf(av1, bv.z, acc[1][2]);
            acc[1][3] = fmaf(av1, bv.w, acc[1][3]);
            acc[2][0] = fmaf(av2, bv.x, acc[2][0]);
            acc[2][1] = fmaf(av2, bv.y, acc[2][1]);
            acc[2][2] = fmaf(av2, bv.z, acc[2][2]);
            acc[2][3] = fmaf(av2, bv.w, acc[2][3]);
            acc[3][0] = fmaf(av3, bv.x, acc[3][0]);
            acc[3][1] = fmaf(av3, bv.y, acc[3][1]);
            acc[3][2] = fmaf(av3, bv.z, acc[3][2]);
            acc[3][3] = fmaf(av3, bv.w, acc[3][3]);
        }
    }

    #pragma unroll
    for (int i = 0; i < 4; ++i) {
        int row = blockIdx.x * BM + ty * 4 + i;
        if (row < M) {
            *(float4*)&C[(size_t)row * N + nBase + n0] =
                make_float4(acc[i][0], acc[i][1], acc[i][2], acc[i][3]);
        }
    }
}

// ---------------------------------------------------------------------------
// Aggregation: one wave per node, float4 (16B) per lane.
// Lanes split into EPL = 64/(F/4) row-groups; each load instruction fetches
// EPL different edge rows (1KB total). Edge id per group via one per-lane-
// indexed shfl. Cross-group combine via shfl-add at the end.
// out_v = d_v * (sum_e w_e h_s + d_v h_v) + bias  [, relu]
// ---------------------------------------------------------------------------
template <int F, bool RELU>
__global__ __launch_bounds__(256) void agg_k(const float* __restrict__ h,
                                             const float* __restrict__ dinv,
                                             const int* __restrict__ row_start,
                                             const int* __restrict__ csr_src,
                                             const float* __restrict__ csr_w,
                                             const float* __restrict__ bias,
                                             float* __restrict__ out) {
    constexpr int LPR = F / 4;     // lanes per row: 32 (F=128) or 16 (F=64)
    constexpr int EPL = 64 / LPR;  // edges per load: 2 or 4
    int wid = (blockIdx.x * 256 + threadIdx.x) >> 6;
    int lane = threadIdx.x & 63;
    if (wid >= N_NODES) return;
    const int v = wid;
    const int grp = lane / LPR;
    const int l = lane % LPR;
    const float dv = dinv[v];

    const float* hL = h + l * 4;   // this lane's feature quad base

    // self-loop (group 0 only, via weight)
    float4 acc;
    {
        float4 t = *(const float4*)&hL[(size_t)v * F];
        float wv = (grp == 0) ? dv : 0.f;
        acc.x = wv * t.x; acc.y = wv * t.y; acc.z = wv * t.z; acc.w = wv * t.w;
    }

    const int e0 = row_start[v], e1 = row_start[v + 1];
    for (int e = e0; e < e1; e += 64) {
        const int cnt = min(64, e1 - e);
        const int c1 = cnt - 1;
        int s = 0; float w = 0.f;
        if (lane < cnt) { s = csr_src[e + lane]; w = csr_w[e + lane]; }

        for (int j = 0; j < cnt; j += 4 * EPL) {
            int idx0 = j + 0 * EPL + grp;
            int idx1 = j + 1 * EPL + grp;
            int idx2 = j + 2 * EPL + grp;
            int idx3 = j + 3 * EPL + grp;
            int i0 = min(idx0, c1), i1 = min(idx1, c1),
                i2 = min(idx2, c1), i3 = min(idx3, c1);
            int   ss0 = __shfl(s, i0), ss1 = __shfl(s, i1),
                  ss2 = __shfl(s, i2), ss3 = __shfl(s, i3);
            float ww0 = __shfl(w, i0), ww1 = __shfl(w, i1),
                  ww2 = __shfl(w, i2), ww3 = __shfl(w, i3);
            if (idx0 >= cnt) ww0 = 0.f;
            if (idx1 >= cnt) ww1 = 0.f;
            if (idx2 >= cnt) ww2 = 0.f;
            if (idx3 >= cnt) ww3 = 0.f;
            float4 t0 = *(const float4*)&hL[(size_t)ss0 * F];
            float4 t1 = *(const float4*)&hL[(size_t)ss1 * F];
            float4 t2 = *(const float4*)&hL[(size_t)ss2 * F];
            float4 t3 = *(const float4*)&hL[(size_t)ss3 * F];
            acc.x = fmaf(ww0, t0.x, acc.x); acc.y = fmaf(ww0, t0.y, acc.y);
            acc.z = fmaf(ww0, t0.z, acc.z); acc.w = fmaf(ww0, t0.w, acc.w);
            acc.x = fmaf(ww1, t1.x, acc.x); acc.y = fmaf(ww1, t1.y, acc.y);
            acc.z = fmaf(ww1, t1.z, acc.z); acc.w = fmaf(ww1, t1.w, acc.w);
            acc.x = fmaf(ww2, t2.x, acc.x); acc.y = fmaf(ww2, t2.y, acc.y);
            acc.z = fmaf(ww2, t2.z, acc.z); acc.w = fmaf(ww2, t2.w, acc.w);
            acc.x = fmaf(ww3, t3.x, acc.x); acc.y = fmaf(ww3, t3.y, acc.y);
            acc.z = fmaf(ww3, t3.z, acc.z); acc.w = fmaf(ww3, t3.w, acc.w);
        }
    }

    // cross-group combine: fold group g>=EPL/2.. down to group 0
    if constexpr (EPL == 4) {
        acc.x += __shfl(acc.x, lane + 32);
        acc.y += __shfl(acc.y, lane + 32);
        acc.z += __shfl(acc.z, lane + 32);
        acc.w += __shfl(acc.w, lane + 32);
        acc.x += __shfl(acc.x, lane + 16);
        acc.y += __shfl(acc.y, lane + 16);
        acc.z += __shfl(acc.z, lane + 16);
        acc.w += __shfl(acc.w, lane + 16);
    } else {
        acc.x += __shfl(acc.x, lane + 32);
        acc.y += __shfl(acc.y, lane + 32);
        acc.z += __shfl(acc.z, lane + 32);
        acc.w += __shfl(acc.w, lane + 32);
    }

    if (grp == 0) {
        float4 o;
        o.x = dv * acc.x + bias[l * 4 + 0];
        o.y = dv * acc.y + bias[l * 4 + 1];
        o.z = dv * acc.z + bias[l * 4 + 2];
        o.w = dv * acc.w + bias[l * 4 + 3];
        if (RELU) {
            o.x = fmaxf(o.x, 0.f); o.y = fmaxf(o.y, 0.f);
            o.z = fmaxf(o.z, 0.f); o.w = fmaxf(o.w, 0.f);
        }
        *(float4*)&out[(size_t)v * F + l * 4] = o;
    }
}

extern "C" void kernel_launch(void* const* d_in, const int* in_sizes, int n_in,
                              void* d_out, int out_size, void* d_ws, size_t ws_size,
                              hipStream_t stream) {
    const float* x        = (const float*)d_in[0];   // [50000,128]
    const float* W1       = (const float*)d_in[1];   // [128,128]
    const float* b1       = (const float*)d_in[2];   // [128]
    const float* W2       = (const float*)d_in[3];   // [128,64]
    const float* b2       = (const float*)d_in[4];   // [64]
    const int*   ei       = (const int*)d_in[5];     // [2,800000] delivered as int32
    float* out = (float*)d_out;                      // [50000,64]

    char* ws = (char*)d_ws;
    int*   deg       = (int*)(ws + OFF_DEG);
    int*   cursor    = (int*)(ws + OFF_CUR);
    int*   row_start = (int*)(ws + OFF_ROW);
    int*   bsums     = (int*)(ws + OFF_BS);
    float* dinv      = (float*)(ws + OFF_DINV);
    int*   csr_src   = (int*)(ws + OFF_CSR);
    float* csr_w     = (float*)(ws + OFF_CSRW);
    float* h1        = (float*)(ws + OFF_H1);
    float* out1      = (float*)(ws + OFF_OUT1);
    float* h2        = (float*)(ws + OFF_H1);  // reuse: h1 dead after agg1

    // zero deg + cursor
    hipMemsetAsync(ws + OFF_DEG, 0, OFF_ROW - OFF_DEG, stream);

    const int nbE = (N_EDGES + 255) / 256;   // 3125
    const int nbN = (N_NODES + 255) / 256;   // 196

    count_deg_k<<<nbE, 256, 0, stream>>>(ei, deg);
    scan1_k<<<nbN, 256, 0, stream>>>(deg, row_start, bsums, dinv);
    scan2_k<<<1, 256, 0, stream>>>(bsums, nbN);
    scan3_k<<<nbN, 256, 0, stream>>>(row_start, bsums);
    fill_k<<<nbE, 256, 0, stream>>>(ei, row_start, cursor, dinv, csr_src, csr_w);

    const int mBlocks = (N_NODES + 63) / 64;  // 782
    gemm_blds<128><<<dim3(mBlocks, 2), 256, 0, stream>>>(x, W1, h1, N_NODES);
    agg_k<128, true><<<(N_NODES + 3) / 4, 256, 0, stream>>>(h1, dinv, row_start, csr_src, csr_w, b1, out1);
    gemm_blds<64><<<dim3(mBlocks, 1), 256, 0, stream>>>(out1, W2, h2, N_NODES);
    agg_k<64, false><<<(N_NODES + 3) / 4, 256, 0, stream>>>(h2, dinv, row_start, csr_src, csr_w, b2, out);
}